// Round 9
// baseline (1504.998 us; speedup 1.0000x reference)
//
#include <hip/hip_runtime.h>
#include <math.h>

// Problem constants
#define N_IMAGE   128
#define N_CAPTION 32
#define N_REGION  36
#define N_WORD    24
#define EMBED     1024
#define EPSV      1e-8f

// Workspace layout (float offsets)
#define WS_W1 0            // 64*64 weight-normed out1 W
#define WS_W2 4096         // 64 weight-normed out2 row
#define WS_S  4160         // 32 captions * 24 words * 8 kernels
#define WS_QN 10304        // 32 captions * 24 words * 32 blocks

// ---------------------------------------------------------------------------
// Kernel 1: weight-norm the two linear layers (tiny, 1 block)
// ---------------------------------------------------------------------------
__global__ __launch_bounds__(64) void prep_weights_k(
    const float* __restrict__ v1, const float* __restrict__ g1,
    const float* __restrict__ v2, const float* __restrict__ g2,
    float* __restrict__ ws) {
  const int j = threadIdx.x;  // 64 threads
  float s = 0.f;
  for (int c0 = 0; c0 < 64; c0++) { float x = v1[j * 64 + c0]; s += x * x; }
  const float sc = g1[j] / sqrtf(s);
  for (int c0 = 0; c0 < 64; c0++) ws[WS_W1 + j * 64 + c0] = v1[j * 64 + c0] * sc;
  float s2 = 0.f;
  for (int c0 = 0; c0 < 64; c0++) { float x = v2[c0]; s2 += x * x; }
  ws[WS_W2 + j] = v2[j] * (g2[0] / sqrtf(s2));
}

// ---------------------------------------------------------------------------
// Kernel 2: per-caption precompute: words_sim softmax, adjacency, S[i][k],
// cap block-norms qn[w][f].  One block per caption.  (unchanged)
// ---------------------------------------------------------------------------
__global__ __launch_bounds__(256) void cap_prep_k(
    const float* __restrict__ captions, const int* __restrict__ depends,
    const float* __restrict__ mean_k, const float* __restrict__ prec_k,
    float* __restrict__ ws) {
  __shared__ __align__(16) float capT[24][132];
  __shared__ float partB[2304];   // 4 groups * 576
  __shared__ float wsL[24][25];
  __shared__ float adjL[24][24];

  const int c = blockIdx.x, tid = threadIdx.x;
  const float* capC = captions + c * N_WORD * EMBED;

  const int g = tid / 36, t = tid % 36;
  const int i0 = (t / 6) * 4, j0 = (t % 6) * 4;
  const bool act = tid < 144;
  float acc[4][4] = {};
  for (int k0 = 0; k0 < EMBED; k0 += 128) {
    for (int idx = tid; idx < 24 * 32; idx += 256) {
      int r = idx >> 5, q = idx & 31;
      *(float4*)&capT[r][q * 4] = *(const float4*)(capC + r * EMBED + k0 + q * 4);
    }
    __syncthreads();
    if (act) {
#pragma unroll
      for (int q8 = 0; q8 < 8; q8++) {
        const int q = g * 8 + q8;
        float4 av[4], bv[4];
#pragma unroll
        for (int a = 0; a < 4; a++) av[a] = *(const float4*)&capT[i0 + a][q * 4];
#pragma unroll
        for (int b = 0; b < 4; b++) bv[b] = *(const float4*)&capT[j0 + b][q * 4];
#pragma unroll
        for (int a = 0; a < 4; a++)
#pragma unroll
          for (int b = 0; b < 4; b++)
            acc[a][b] += av[a].x * bv[b].x + av[a].y * bv[b].y +
                         av[a].z * bv[b].z + av[a].w * bv[b].w;
      }
    }
    __syncthreads();
  }
  if (act)
#pragma unroll
    for (int a = 0; a < 4; a++)
#pragma unroll
      for (int b = 0; b < 4; b++)
        partB[g * 576 + (i0 + a) * 24 + (j0 + b)] = acc[a][b];
  __syncthreads();
  for (int p = tid; p < 576; p += 256)
    wsL[p / 24][p % 24] = partB[p] + partB[p + 576] + partB[p + 1152] + partB[p + 1728];
  {
    float* ap = &adjL[0][0];
    for (int p = tid; p < 576; p += 256) ap[p] = 0.f;
  }
  __syncthreads();
  if (tid < 24) {
    const int i = tid;
    float m = -1e30f;
    for (int j = 0; j < 24; j++) m = fmaxf(m, wsL[i][j]);
    float ssum = 0.f;
    for (int j = 0; j < 24; j++) {
      float e = expf(4.0f * (wsL[i][j] - m));
      wsL[i][j] = e; ssum += e;
    }
    float inv = 1.0f / ssum;
    for (int j = 0; j < 24; j++) wsL[i][j] *= inv;
  }
  __syncthreads();
  if (tid >= 1 && tid < 23) {
    int r = depends[c * 46 + tid * 2];
    int cc = depends[c * 46 + tid * 2 + 1];
    if ((unsigned)r < 24u && (unsigned)cc < 24u) {
      adjL[r][cc] = 1.f;
      adjL[cc][r] = 1.f;
    }
  }
  __syncthreads();
  if (tid < 24) adjL[tid][tid] += 1.f;
  __syncthreads();
  if (tid < 24) {
    const int i = tid;
    float mk[8], pk2[8];
#pragma unroll
    for (int k = 0; k < 8; k++) {
      mk[k] = mean_k[k];
      float p = prec_k[k];
      pk2[k] = 1e-14f + p * p;
    }
    float s2 = 0.f;
    for (int j = 0; j < 24; j++) {
      float a = adjL[i][j] * wsL[i][j];
      s2 += a * a;
    }
    const float inv = 1.0f / (sqrtf(s2) + EPSV);
    float accS[8] = {};
    for (int j = 0; j < 24; j++) {
      const float adj_ij = adjL[i][j];
      if (adj_ij != 0.f) {
        const float nb = adj_ij * wsL[i][j] * inv;
        float wk[8], ssum = 0.f;
#pragma unroll
        for (int k = 0; k < 8; k++) {
          float d = nb - mk[k];
          wk[k] = expf(-0.5f * d * d / pk2[k]);
          ssum += wk[k];
        }
        const float invs = adj_ij / ssum;
#pragma unroll
        for (int k = 0; k < 8; k++) accS[k] += wk[k] * invs;
      }
    }
#pragma unroll
    for (int k = 0; k < 8; k++) ws[WS_S + (c * 24 + i) * 8 + k] = accS[k];
  }
  for (int p = tid; p < 768; p += 256) {
    const int w = p >> 5, f = p & 31;
    const float* q = capC + w * EMBED + f * 32;
    float s = 0.f;
#pragma unroll
    for (int d = 0; d < 32; d += 4) {
      float4 v = *(const float4*)(q + d);
      s += v.x * v.x + v.y * v.y + v.z * v.z + v.w * v.w;
    }
    ws[WS_QN + (c * 24 + w) * 32 + f] = sqrtf(s);
  }
}

// ---------------------------------------------------------------------------
// Kernel 3: main — one block per (image n, caption c) pair.
// R9 (clean resubmit of the unmeasured R5 experiment; R8's dual-variant +
//     hipFuncGetAttributes host query is the suspect for "container failed
//     twice" and has been removed — kernel_launch now does stream launches
//     only, like the R0-R4 submissions that ran fine):
//     fused kernel (R3 structure) + amdgpu_waves_per_eu(3) -> VGPR cap ~168.
//     Empirical map: launch_bounds(256,w) caps VGPR at 256/w (w=2 -> 128,
//     which spilled 794MB of scratch; the spill lives in stages 3/4 per the
//     R4 split experiment). The direct attribute expresses the unreachable
//     150-170 window: R0's natural pressure was 176 with zero spill, so a
//     168 cap shaves ~8 slack regs -> 3 waves/SIMD (12 waves/CU, 1.5x R0)
//     with no scratch traffic. LDS 38.9KB allows 4 blocks/CU (not binding).
// ---------------------------------------------------------------------------
__global__ __launch_bounds__(256) __attribute__((amdgpu_waves_per_eu(3)))
void main_k(
    const float* __restrict__ images, const float* __restrict__ captions,
    const float* __restrict__ conv_w, const float* __restrict__ out1_b,
    const float* __restrict__ out2_b, const float* __restrict__ ws,
    float* __restrict__ out) {
  // smemA: imgT (swizzled, pitch 132) / split-K partials (3456) / W1t (64x68)
  // smemB: capT (stage1, swizzled)    / hiddenL (stage4, pitch 68)
  // smemC: attnT [36][28]             / {Ss[192], w2s[64], b1s[64], sred[24]}
  __shared__ __align__(16) float smemA[36 * 132];   // 19008 B
  __shared__ __align__(16) float smemB[24 * 132];   // 12672 B
  __shared__ __align__(16) float smemC[36 * 28];    //  4032 B
  __shared__ float tnodeL[24][33];                  //  3168 B   => 38880 B

  const int tid = threadIdx.x;
  const int bid = blockIdx.x;
  const int n = bid >> 5, c = bid & 31;
  const float* imgN = images + n * N_REGION * EMBED;
  const float* capC = captions + c * N_WORD * EMBED;

  // ============ stage 1: attn_raw = leaky_relu(img @ cap^T) ============
  // 4x4 register tiles (36x24 outputs), 4-way split-K: 216 active threads.
  const int g1 = tid / 54, t1 = tid % 54;
  const int r0 = (t1 / 6) * 4, w0s1 = (t1 % 6) * 4;
  const bool act1 = tid < 216;
  const int si = (r0 >> 2) & 7, sc = (w0s1 >> 2) & 7;  // bank swizzles
  float acc1[4][4] = {};

  for (int k0 = 0; k0 < EMBED; k0 += 128) {
    // stage img chunk (rows 0..35, 32x16B units, unit idx XOR (r>>2)&7)
    for (int idx = tid; idx < 36 * 32; idx += 256) {
      const int r = idx >> 5, q = idx & 31;
      *(float4*)&smemA[r * 132 + (q ^ ((r >> 2) & 7)) * 4] =
          *(const float4*)(imgN + r * EMBED + k0 + q * 4);
    }
    // stage cap chunk
    for (int idx = tid; idx < 24 * 32; idx += 256) {
      const int r = idx >> 5, q = idx & 31;
      *(float4*)&smemB[r * 132 + (q ^ ((r >> 2) & 7)) * 4] =
          *(const float4*)(capC + r * EMBED + k0 + q * 4);
    }
    __syncthreads();
    if (act1) {
#pragma unroll
      for (int q8 = 0; q8 < 8; q8++) {
        const int q = g1 * 8 + q8;
        float4 av[4], bv[4];
#pragma unroll
        for (int a = 0; a < 4; a++)
          av[a] = *(const float4*)&smemA[(r0 + a) * 132 + (q ^ si) * 4];
#pragma unroll
        for (int b = 0; b < 4; b++)
          bv[b] = *(const float4*)&smemB[(w0s1 + b) * 132 + (q ^ sc) * 4];
#pragma unroll
        for (int a = 0; a < 4; a++)
#pragma unroll
          for (int b = 0; b < 4; b++)
            acc1[a][b] += av[a].x * bv[b].x + av[a].y * bv[b].y +
                          av[a].z * bv[b].z + av[a].w * bv[b].w;
      }
    }
    __syncthreads();
  }
  {
    float* part = smemA;  // 4*864 = 3456 floats, imgT dead
    if (act1) {
#pragma unroll
      for (int a = 0; a < 4; a++)
#pragma unroll
        for (int b = 0; b < 4; b++)
          part[g1 * 864 + (r0 + a) * 24 + (w0s1 + b)] = acc1[a][b];
    }
    __syncthreads();
    for (int p = tid; p < 864; p += 256) {
      float s = part[p] + part[p + 864] + part[p + 1728] + part[p + 2592];
      smemC[(p / 24) * 28 + (p % 24)] = (s > 0.f) ? s : 0.1f * s;  // leaky 0.1
    }
    __syncthreads();
  }

  // ============ stage 2: l2norm over words (per region), softmax over regions ============
  if (tid < 36) {
    const int r = tid;
    float s = 0.f;
    for (int w = 0; w < 24; w++) { float x = smemC[r * 28 + w]; s += x * x; }
    const float inv = 1.f / (sqrtf(s) + EPSV);
    for (int w = 0; w < 24; w++) smemC[r * 28 + w] *= inv;
  }
  __syncthreads();
  if (tid < 24) {
    const int w = tid;
    float m = -1e30f;
    for (int r = 0; r < 36; r++) m = fmaxf(m, smemC[r * 28 + w]);
    float ssum = 0.f;
    for (int r = 0; r < 36; r++) {
      float e = expf(4.0f * (smemC[r * 28 + w] - m));
      smemC[r * 28 + w] = e; ssum += e;
    }
    const float inv = 1.0f / ssum;
    for (int r = 0; r < 36; r++) smemC[r * 28 + w] *= inv;
  }
  __syncthreads();

  // ============ stage 3: wctx in registers + block cosine -> tnode ============
  // 256 threads: (wg = 3 words, dq = 16B unit). ctx kept in 3x float4 regs;
  // cosine partial over this thread's 4 floats, octet shfl_xor reduce (dq&7).
  const int wg = (tid >> 5) * 3;   // 0,3,...,21
  const int dq = tid & 31;
  for (int k0 = 0; k0 < EMBED; k0 += 128) {
    for (int idx = tid; idx < 36 * 32; idx += 256) {
      const int r = idx >> 5, q = idx & 31;
      *(float4*)&smemA[r * 132 + (q ^ ((r >> 2) & 7)) * 4] =
          *(const float4*)(imgN + r * EMBED + k0 + q * 4);
    }
    __syncthreads();
    {
      // cap slices direct from global (L2-resident; issued early to hide latency)
      float4 cv0 = *(const float4*)(capC + (wg + 0) * EMBED + k0 + dq * 4);
      float4 cv1 = *(const float4*)(capC + (wg + 1) * EMBED + k0 + dq * 4);
      float4 cv2 = *(const float4*)(capC + (wg + 2) * EMBED + k0 + dq * 4);
      float4 a0 = make_float4(0.f, 0.f, 0.f, 0.f), a1 = a0, a2 = a0;
      for (int r = 0; r < 36; r++) {
        float4 iv = *(const float4*)&smemA[r * 132 + (dq ^ ((r >> 2) & 7)) * 4];
        const float aw0 = smemC[r * 28 + wg + 0];
        const float aw1 = smemC[r * 28 + wg + 1];
        const float aw2 = smemC[r * 28 + wg + 2];
        a0.x += aw0 * iv.x; a0.y += aw0 * iv.y; a0.z += aw0 * iv.z; a0.w += aw0 * iv.w;
        a1.x += aw1 * iv.x; a1.y += aw1 * iv.y; a1.z += aw1 * iv.z; a1.w += aw1 * iv.w;
        a2.x += aw2 * iv.x; a2.y += aw2 * iv.y; a2.z += aw2 * iv.z; a2.w += aw2 * iv.w;
      }
      float nu0 = a0.x * cv0.x + a0.y * cv0.y + a0.z * cv0.z + a0.w * cv0.w;
      float nu1 = a1.x * cv1.x + a1.y * cv1.y + a1.z * cv1.z + a1.w * cv1.w;
      float nu2 = a2.x * cv2.x + a2.y * cv2.y + a2.z * cv2.z + a2.w * cv2.w;
      float cz0 = a0.x * a0.x + a0.y * a0.y + a0.z * a0.z + a0.w * a0.w;
      float cz1 = a1.x * a1.x + a1.y * a1.y + a1.z * a1.z + a1.w * a1.w;
      float cz2 = a2.x * a2.x + a2.y * a2.y + a2.z * a2.z + a2.w * a2.w;
#pragma unroll
      for (int m = 1; m < 8; m <<= 1) {
        nu0 += __shfl_xor(nu0, m); cz0 += __shfl_xor(cz0, m);
        nu1 += __shfl_xor(nu1, m); cz1 += __shfl_xor(cz1, m);
        nu2 += __shfl_xor(nu2, m); cz2 += __shfl_xor(cz2, m);
      }
      if ((dq & 7) == 0) {
        const int f = (k0 >> 5) + (dq >> 3);
        const float* qnp = ws + WS_QN + (c * 24 + wg) * 32 + f;
        tnodeL[wg + 0][f] = nu0 / fmaxf(qnp[0]  * sqrtf(cz0), EPSV);
        tnodeL[wg + 1][f] = nu1 / fmaxf(qnp[32] * sqrtf(cz1), EPSV);
        tnodeL[wg + 2][f] = nu2 / fmaxf(qnp[64] * sqrtf(cz2), EPSV);
      }
    }
    __syncthreads();
  }

  // ============ stage 4: graph-conv collapse + weight-normed MLP ============
  float* W1t = smemA;          // W1t[col*68 + j] = W1[j][col]; 64*68 = 4352 floats
  float* hiddenL = smemB;      // pitch 68 (17 units -> conflict-free row access)
  float* Ss = smemC;           // 192 floats S[w*8+k]
  float* w2s = smemC + 192;
  float* b1s = smemC + 256;
  float* sred = smemC + 320;
  for (int idx = tid; idx < 4096; idx += 256) {
    const int j = idx >> 6, col = idx & 63;
    W1t[col * 68 + j] = ws[WS_W1 + idx];
  }
  for (int p = tid; p < 192; p += 256) Ss[p] = ws[WS_S + c * 192 + p];
  if (tid < 64) w2s[tid] = ws[WS_W2 + tid];
  else if (tid < 128) b1s[tid - 64] = out1_b[tid - 64];
  __syncthreads();

  // hidden[w][k*8+o] = S[w,k] * sum_f tnode[w,f]*conv_w[k,f,o]
  for (int p = tid; p < 1536; p += 256) {
    const int w = p >> 6, col = p & 63, k = col >> 3, o = col & 7;
    const float* cw = conv_w + k * 256 + o;
    float tacc = 0.f;
#pragma unroll
    for (int f = 0; f < 32; f++) tacc += tnodeL[w][f] * cw[f * 8];
    hiddenL[w * 68 + col] = Ss[w * 8 + k] * tacc;
  }
  __syncthreads();

  // h = tanh(hidden @ W1^T + b1): each thread -> 4 consecutive j outputs
  float hv[2][4];
  {
    int pc = 0;
    for (int p = tid; p < 384; p += 256, pc++) {
      const int w = p >> 4, j0 = (p & 15) * 4;
      float ax = b1s[j0 + 0], ay = b1s[j0 + 1], az = b1s[j0 + 2], aww = b1s[j0 + 3];
      for (int col = 0; col < 64; col += 4) {
        float4 h4 = *(const float4*)&hiddenL[w * 68 + col];
        float4 wv0 = *(const float4*)&W1t[(col + 0) * 68 + j0];
        float4 wv1 = *(const float4*)&W1t[(col + 1) * 68 + j0];
        float4 wv2 = *(const float4*)&W1t[(col + 2) * 68 + j0];
        float4 wv3 = *(const float4*)&W1t[(col + 3) * 68 + j0];
        ax  += h4.x * wv0.x + h4.y * wv1.x + h4.z * wv2.x + h4.w * wv3.x;
        ay  += h4.x * wv0.y + h4.y * wv1.y + h4.z * wv2.y + h4.w * wv3.y;
        az  += h4.x * wv0.z + h4.y * wv1.z + h4.z * wv2.z + h4.w * wv3.z;
        aww += h4.x * wv0.w + h4.y * wv1.w + h4.z * wv2.w + h4.w * wv3.w;
      }
      hv[pc][0] = tanhf(ax); hv[pc][1] = tanhf(ay);
      hv[pc][2] = tanhf(az); hv[pc][3] = tanhf(aww);
    }
    __syncthreads();  // all reads of hiddenL complete before overwrite
    pc = 0;
    for (int p = tid; p < 384; p += 256, pc++) {
      const int w = p >> 4, j0 = (p & 15) * 4;
      hiddenL[w * 68 + j0 + 0] = hv[pc][0]; hiddenL[w * 68 + j0 + 1] = hv[pc][1];
      hiddenL[w * 68 + j0 + 2] = hv[pc][2]; hiddenL[w * 68 + j0 + 3] = hv[pc][3];
    }
    __syncthreads();
  }

  // s[w] = h[w]·w2 + b2; output = mean over words
  if (tid < 24) {
    const int w = tid;
    float sv = out2_b[0];
    for (int j = 0; j < 64; j++) sv += hiddenL[w * 68 + j] * w2s[j];
    sred[w] = sv;
  }
  __syncthreads();
  if (tid == 0) {
    float s = 0.f;
    for (int w = 0; w < 24; w++) s += sred[w];
    out[n * 32 + c] = s * (1.0f / 24.0f);
  }
}

// ---------------------------------------------------------------------------
extern "C" void kernel_launch(void* const* d_in, const int* in_sizes, int n_in,
                              void* d_out, int out_size, void* d_ws, size_t ws_size,
                              hipStream_t stream) {
  const float* images   = (const float*)d_in[0];
  const float* captions = (const float*)d_in[1];
  const int*   depends  = (const int*)d_in[2];
  // d_in[3] cap_lens: unused by reference math (all == N_WORD)
  const float* mean_k   = (const float*)d_in[4];
  const float* prec_k   = (const float*)d_in[5];
  const float* conv_w   = (const float*)d_in[6];
  const float* out1_v   = (const float*)d_in[7];
  const float* out1_g   = (const float*)d_in[8];
  const float* out1_b   = (const float*)d_in[9];
  const float* out2_v   = (const float*)d_in[10];
  const float* out2_g   = (const float*)d_in[11];
  const float* out2_b   = (const float*)d_in[12];
  float* ws  = (float*)d_ws;
  float* out = (float*)d_out;

  prep_weights_k<<<dim3(1), dim3(64), 0, stream>>>(out1_v, out1_g, out2_v, out2_g, ws);
  cap_prep_k<<<dim3(32), dim3(256), 0, stream>>>(captions, depends, mean_k, prec_k, ws);
  main_k<<<dim3(N_IMAGE * N_CAPTION), dim3(256), 0, stream>>>(
      images, captions, conv_w, out1_b, out2_b, ws, out);
}

// Round 10
// 707.842 us; speedup vs baseline: 2.1262x; 2.1262x over previous
//
#include <hip/hip_runtime.h>
#include <math.h>

// Problem constants
#define N_IMAGE   128
#define N_CAPTION 32
#define N_REGION  36
#define N_WORD    24
#define EMBED     1024
#define EPSV      1e-8f

// Workspace layout (float offsets)
#define WS_W1 0            // 64*64 weight-normed out1 W
#define WS_W2 4096         // 64 weight-normed out2 row
#define WS_S  4160         // 32 captions * 24 words * 8 kernels
#define WS_QN 10304        // 32 captions * 24 words * 32 blocks

// ---------------------------------------------------------------------------
// Kernel 1: weight-norm the two linear layers (tiny, 1 block)
// ---------------------------------------------------------------------------
__global__ __launch_bounds__(64) void prep_weights_k(
    const float* __restrict__ v1, const float* __restrict__ g1,
    const float* __restrict__ v2, const float* __restrict__ g2,
    float* __restrict__ ws) {
  const int j = threadIdx.x;  // 64 threads
  float s = 0.f;
  for (int c0 = 0; c0 < 64; c0++) { float x = v1[j * 64 + c0]; s += x * x; }
  const float sc = g1[j] / sqrtf(s);
  for (int c0 = 0; c0 < 64; c0++) ws[WS_W1 + j * 64 + c0] = v1[j * 64 + c0] * sc;
  float s2 = 0.f;
  for (int c0 = 0; c0 < 64; c0++) { float x = v2[c0]; s2 += x * x; }
  ws[WS_W2 + j] = v2[j] * (g2[0] / sqrtf(s2));
}

// ---------------------------------------------------------------------------
// Kernel 2: per-caption precompute: words_sim softmax, adjacency, S[i][k],
// cap block-norms qn[w][f].  One block per caption.  (unchanged)
// ---------------------------------------------------------------------------
__global__ __launch_bounds__(256) void cap_prep_k(
    const float* __restrict__ captions, const int* __restrict__ depends,
    const float* __restrict__ mean_k, const float* __restrict__ prec_k,
    float* __restrict__ ws) {
  __shared__ __align__(16) float capT[24][132];
  __shared__ float partB[2304];   // 4 groups * 576
  __shared__ float wsL[24][25];
  __shared__ float adjL[24][24];

  const int c = blockIdx.x, tid = threadIdx.x;
  const float* capC = captions + c * N_WORD * EMBED;

  const int g = tid / 36, t = tid % 36;
  const int i0 = (t / 6) * 4, j0 = (t % 6) * 4;
  const bool act = tid < 144;
  float acc[4][4] = {};
  for (int k0 = 0; k0 < EMBED; k0 += 128) {
    for (int idx = tid; idx < 24 * 32; idx += 256) {
      int r = idx >> 5, q = idx & 31;
      *(float4*)&capT[r][q * 4] = *(const float4*)(capC + r * EMBED + k0 + q * 4);
    }
    __syncthreads();
    if (act) {
#pragma unroll
      for (int q8 = 0; q8 < 8; q8++) {
        const int q = g * 8 + q8;
        float4 av[4], bv[4];
#pragma unroll
        for (int a = 0; a < 4; a++) av[a] = *(const float4*)&capT[i0 + a][q * 4];
#pragma unroll
        for (int b = 0; b < 4; b++) bv[b] = *(const float4*)&capT[j0 + b][q * 4];
#pragma unroll
        for (int a = 0; a < 4; a++)
#pragma unroll
          for (int b = 0; b < 4; b++)
            acc[a][b] += av[a].x * bv[b].x + av[a].y * bv[b].y +
                         av[a].z * bv[b].z + av[a].w * bv[b].w;
      }
    }
    __syncthreads();
  }
  if (act)
#pragma unroll
    for (int a = 0; a < 4; a++)
#pragma unroll
      for (int b = 0; b < 4; b++)
        partB[g * 576 + (i0 + a) * 24 + (j0 + b)] = acc[a][b];
  __syncthreads();
  for (int p = tid; p < 576; p += 256)
    wsL[p / 24][p % 24] = partB[p] + partB[p + 576] + partB[p + 1152] + partB[p + 1728];
  {
    float* ap = &adjL[0][0];
    for (int p = tid; p < 576; p += 256) ap[p] = 0.f;
  }
  __syncthreads();
  if (tid < 24) {
    const int i = tid;
    float m = -1e30f;
    for (int j = 0; j < 24; j++) m = fmaxf(m, wsL[i][j]);
    float ssum = 0.f;
    for (int j = 0; j < 24; j++) {
      float e = expf(4.0f * (wsL[i][j] - m));
      wsL[i][j] = e; ssum += e;
    }
    float inv = 1.0f / ssum;
    for (int j = 0; j < 24; j++) wsL[i][j] *= inv;
  }
  __syncthreads();
  if (tid >= 1 && tid < 23) {
    int r = depends[c * 46 + tid * 2];
    int cc = depends[c * 46 + tid * 2 + 1];
    if ((unsigned)r < 24u && (unsigned)cc < 24u) {
      adjL[r][cc] = 1.f;
      adjL[cc][r] = 1.f;
    }
  }
  __syncthreads();
  if (tid < 24) adjL[tid][tid] += 1.f;
  __syncthreads();
  if (tid < 24) {
    const int i = tid;
    float mk[8], pk2[8];
#pragma unroll
    for (int k = 0; k < 8; k++) {
      mk[k] = mean_k[k];
      float p = prec_k[k];
      pk2[k] = 1e-14f + p * p;
    }
    float s2 = 0.f;
    for (int j = 0; j < 24; j++) {
      float a = adjL[i][j] * wsL[i][j];
      s2 += a * a;
    }
    const float inv = 1.0f / (sqrtf(s2) + EPSV);
    float accS[8] = {};
    for (int j = 0; j < 24; j++) {
      const float adj_ij = adjL[i][j];
      if (adj_ij != 0.f) {
        const float nb = adj_ij * wsL[i][j] * inv;
        float wk[8], ssum = 0.f;
#pragma unroll
        for (int k = 0; k < 8; k++) {
          float d = nb - mk[k];
          wk[k] = expf(-0.5f * d * d / pk2[k]);
          ssum += wk[k];
        }
        const float invs = adj_ij / ssum;
#pragma unroll
        for (int k = 0; k < 8; k++) accS[k] += wk[k] * invs;
      }
    }
#pragma unroll
    for (int k = 0; k < 8; k++) ws[WS_S + (c * 24 + i) * 8 + k] = accS[k];
  }
  for (int p = tid; p < 768; p += 256) {
    const int w = p >> 5, f = p & 31;
    const float* q = capC + w * EMBED + f * 32;
    float s = 0.f;
#pragma unroll
    for (int d = 0; d < 32; d += 4) {
      float4 v = *(const float4*)(q + d);
      s += v.x * v.x + v.y * v.y + v.z * v.z + v.w * v.w;
    }
    ws[WS_QN + (c * 24 + w) * 32 + f] = sqrtf(s);
  }
}

// ---------------------------------------------------------------------------
// Kernel 3: main — one block per (image n, caption c) pair.
// R10: knob space exhausted (waves_per_eu(3) == launch_bounds(256,3) == 84
//      VGPR, R9; cap = 256/n, the 150-170 window is unreachable). Spill is
//      schedule-induced in stages 3/4 (R4 split: ctx_mlp_k alone spilled the
//      full 794MB). Structural pressure surgery to fit the 128 cap:
//      - stage 3: cv loads moved AFTER the r-loop (-12 live regs across 36
//        iters); r-loop pinned to unroll 4 (stop auto-unroll bloat)
//      - stage 4: f-loop unroll 8 (was full 32), col-loop unroll 4 (was 16)
//      - stage 1: bv one-at-a-time (R4 attn_k variant, verified) -12 regs
// ---------------------------------------------------------------------------
__global__ __launch_bounds__(256, 2) void main_k(
    const float* __restrict__ images, const float* __restrict__ captions,
    const float* __restrict__ conv_w, const float* __restrict__ out1_b,
    const float* __restrict__ out2_b, const float* __restrict__ ws,
    float* __restrict__ out) {
  // smemA: imgT (swizzled, pitch 132) / split-K partials (3456) / W1t (64x68)
  // smemB: capT (stage1, swizzled)    / hiddenL (stage4, pitch 68)
  // smemC: attnT [36][28]             / {Ss[192], w2s[64], b1s[64], sred[24]}
  __shared__ __align__(16) float smemA[36 * 132];   // 19008 B
  __shared__ __align__(16) float smemB[24 * 132];   // 12672 B
  __shared__ __align__(16) float smemC[36 * 28];    //  4032 B
  __shared__ float tnodeL[24][33];                  //  3168 B   => 38880 B

  const int tid = threadIdx.x;
  const int bid = blockIdx.x;
  const int n = bid >> 5, c = bid & 31;
  const float* imgN = images + n * N_REGION * EMBED;
  const float* capC = captions + c * N_WORD * EMBED;

  // ============ stage 1: attn_raw = leaky_relu(img @ cap^T) ============
  // 4x4 register tiles (36x24 outputs), 4-way split-K: 216 active threads.
  const int g1 = tid / 54, t1 = tid % 54;
  const int r0 = (t1 / 6) * 4, w0s1 = (t1 % 6) * 4;
  const bool act1 = tid < 216;
  const int si = (r0 >> 2) & 7, sc = (w0s1 >> 2) & 7;  // bank swizzles
  float acc1[4][4] = {};

  for (int k0 = 0; k0 < EMBED; k0 += 128) {
    // stage img chunk (rows 0..35, 32x16B units, unit idx XOR (r>>2)&7)
    for (int idx = tid; idx < 36 * 32; idx += 256) {
      const int r = idx >> 5, q = idx & 31;
      *(float4*)&smemA[r * 132 + (q ^ ((r >> 2) & 7)) * 4] =
          *(const float4*)(imgN + r * EMBED + k0 + q * 4);
    }
    // stage cap chunk
    for (int idx = tid; idx < 24 * 32; idx += 256) {
      const int r = idx >> 5, q = idx & 31;
      *(float4*)&smemB[r * 132 + (q ^ ((r >> 2) & 7)) * 4] =
          *(const float4*)(capC + r * EMBED + k0 + q * 4);
    }
    __syncthreads();
    if (act1) {
#pragma unroll
      for (int q8 = 0; q8 < 8; q8++) {
        const int q = g1 * 8 + q8;
        float4 av[4];
#pragma unroll
        for (int a = 0; a < 4; a++)
          av[a] = *(const float4*)&smemA[(r0 + a) * 132 + (q ^ si) * 4];
        // bv one-at-a-time: 4x fewer live B regs (verified in R4 attn_k)
#pragma unroll
        for (int b = 0; b < 4; b++) {
          const float4 bv = *(const float4*)&smemB[(w0s1 + b) * 132 + (q ^ sc) * 4];
#pragma unroll
          for (int a = 0; a < 4; a++)
            acc1[a][b] += av[a].x * bv.x + av[a].y * bv.y +
                          av[a].z * bv.z + av[a].w * bv.w;
        }
      }
    }
    __syncthreads();
  }
  {
    float* part = smemA;  // 4*864 = 3456 floats, imgT dead
    if (act1) {
#pragma unroll
      for (int a = 0; a < 4; a++)
#pragma unroll
        for (int b = 0; b < 4; b++)
          part[g1 * 864 + (r0 + a) * 24 + (w0s1 + b)] = acc1[a][b];
    }
    __syncthreads();
    for (int p = tid; p < 864; p += 256) {
      float s = part[p] + part[p + 864] + part[p + 1728] + part[p + 2592];
      smemC[(p / 24) * 28 + (p % 24)] = (s > 0.f) ? s : 0.1f * s;  // leaky 0.1
    }
    __syncthreads();
  }

  // ============ stage 2: l2norm over words (per region), softmax over regions ============
  if (tid < 36) {
    const int r = tid;
    float s = 0.f;
    for (int w = 0; w < 24; w++) { float x = smemC[r * 28 + w]; s += x * x; }
    const float inv = 1.f / (sqrtf(s) + EPSV);
    for (int w = 0; w < 24; w++) smemC[r * 28 + w] *= inv;
  }
  __syncthreads();
  if (tid < 24) {
    const int w = tid;
    float m = -1e30f;
    for (int r = 0; r < 36; r++) m = fmaxf(m, smemC[r * 28 + w]);
    float ssum = 0.f;
    for (int r = 0; r < 36; r++) {
      float e = expf(4.0f * (smemC[r * 28 + w] - m));
      smemC[r * 28 + w] = e; ssum += e;
    }
    const float inv = 1.0f / ssum;
    for (int r = 0; r < 36; r++) smemC[r * 28 + w] *= inv;
  }
  __syncthreads();

  // ============ stage 3: wctx in registers + block cosine -> tnode ============
  // 256 threads: (wg = 3 words, dq = 16B unit). ctx in 3x float4 regs; the
  // r-loop is unroll-pinned and cv loads deferred to after it (pressure).
  const int wg = (tid >> 5) * 3;   // 0,3,...,21
  const int dq = tid & 31;
  for (int k0 = 0; k0 < EMBED; k0 += 128) {
    for (int idx = tid; idx < 36 * 32; idx += 256) {
      const int r = idx >> 5, q = idx & 31;
      *(float4*)&smemA[r * 132 + (q ^ ((r >> 2) & 7)) * 4] =
          *(const float4*)(imgN + r * EMBED + k0 + q * 4);
    }
    __syncthreads();
    {
      float4 a0 = make_float4(0.f, 0.f, 0.f, 0.f), a1 = a0, a2 = a0;
#pragma unroll 4
      for (int r = 0; r < 36; r++) {
        float4 iv = *(const float4*)&smemA[r * 132 + (dq ^ ((r >> 2) & 7)) * 4];
        const float aw0 = smemC[r * 28 + wg + 0];
        const float aw1 = smemC[r * 28 + wg + 1];
        const float aw2 = smemC[r * 28 + wg + 2];
        a0.x += aw0 * iv.x; a0.y += aw0 * iv.y; a0.z += aw0 * iv.z; a0.w += aw0 * iv.w;
        a1.x += aw1 * iv.x; a1.y += aw1 * iv.y; a1.z += aw1 * iv.z; a1.w += aw1 * iv.w;
        a2.x += aw2 * iv.x; a2.y += aw2 * iv.y; a2.z += aw2 * iv.z; a2.w += aw2 * iv.w;
      }
      // cap slices loaded AFTER the ctx loop: not live across it (pressure)
      float4 cv0 = *(const float4*)(capC + (wg + 0) * EMBED + k0 + dq * 4);
      float4 cv1 = *(const float4*)(capC + (wg + 1) * EMBED + k0 + dq * 4);
      float4 cv2 = *(const float4*)(capC + (wg + 2) * EMBED + k0 + dq * 4);
      float nu0 = a0.x * cv0.x + a0.y * cv0.y + a0.z * cv0.z + a0.w * cv0.w;
      float nu1 = a1.x * cv1.x + a1.y * cv1.y + a1.z * cv1.z + a1.w * cv1.w;
      float nu2 = a2.x * cv2.x + a2.y * cv2.y + a2.z * cv2.z + a2.w * cv2.w;
      float cz0 = a0.x * a0.x + a0.y * a0.y + a0.z * a0.z + a0.w * a0.w;
      float cz1 = a1.x * a1.x + a1.y * a1.y + a1.z * a1.z + a1.w * a1.w;
      float cz2 = a2.x * a2.x + a2.y * a2.y + a2.z * a2.z + a2.w * a2.w;
#pragma unroll
      for (int m = 1; m < 8; m <<= 1) {
        nu0 += __shfl_xor(nu0, m); cz0 += __shfl_xor(cz0, m);
        nu1 += __shfl_xor(nu1, m); cz1 += __shfl_xor(cz1, m);
        nu2 += __shfl_xor(nu2, m); cz2 += __shfl_xor(cz2, m);
      }
      if ((dq & 7) == 0) {
        const int f = (k0 >> 5) + (dq >> 3);
        const float* qnp = ws + WS_QN + (c * 24 + wg) * 32 + f;
        tnodeL[wg + 0][f] = nu0 / fmaxf(qnp[0]  * sqrtf(cz0), EPSV);
        tnodeL[wg + 1][f] = nu1 / fmaxf(qnp[32] * sqrtf(cz1), EPSV);
        tnodeL[wg + 2][f] = nu2 / fmaxf(qnp[64] * sqrtf(cz2), EPSV);
      }
    }
    __syncthreads();
  }

  // ============ stage 4: graph-conv collapse + weight-normed MLP ============
  float* W1t = smemA;          // W1t[col*68 + j] = W1[j][col]; 64*68 = 4352 floats
  float* hiddenL = smemB;      // pitch 68 (17 units -> conflict-free row access)
  float* Ss = smemC;           // 192 floats S[w*8+k]
  float* w2s = smemC + 192;
  float* b1s = smemC + 256;
  float* sred = smemC + 320;
  for (int idx = tid; idx < 4096; idx += 256) {
    const int j = idx >> 6, col = idx & 63;
    W1t[col * 68 + j] = ws[WS_W1 + idx];
  }
  for (int p = tid; p < 192; p += 256) Ss[p] = ws[WS_S + c * 192 + p];
  if (tid < 64) w2s[tid] = ws[WS_W2 + tid];
  else if (tid < 128) b1s[tid - 64] = out1_b[tid - 64];
  __syncthreads();

  // hidden[w][k*8+o] = S[w,k] * sum_f tnode[w,f]*conv_w[k,f,o]
  for (int p = tid; p < 1536; p += 256) {
    const int w = p >> 6, col = p & 63, k = col >> 3, o = col & 7;
    const float* cw = conv_w + k * 256 + o;
    float tacc = 0.f;
#pragma unroll 8
    for (int f = 0; f < 32; f++) tacc += tnodeL[w][f] * cw[f * 8];
    hiddenL[w * 68 + col] = Ss[w * 8 + k] * tacc;
  }
  __syncthreads();

  // h = tanh(hidden @ W1^T + b1): each thread -> 4 consecutive j outputs
  float hv[2][4];
  {
    int pc = 0;
    for (int p = tid; p < 384; p += 256, pc++) {
      const int w = p >> 4, j0 = (p & 15) * 4;
      float ax = b1s[j0 + 0], ay = b1s[j0 + 1], az = b1s[j0 + 2], aww = b1s[j0 + 3];
#pragma unroll 4
      for (int col = 0; col < 64; col += 4) {
        float4 h4 = *(const float4*)&hiddenL[w * 68 + col];
        float4 wv0 = *(const float4*)&W1t[(col + 0) * 68 + j0];
        float4 wv1 = *(const float4*)&W1t[(col + 1) * 68 + j0];
        float4 wv2 = *(const float4*)&W1t[(col + 2) * 68 + j0];
        float4 wv3 = *(const float4*)&W1t[(col + 3) * 68 + j0];
        ax  += h4.x * wv0.x + h4.y * wv1.x + h4.z * wv2.x + h4.w * wv3.x;
        ay  += h4.x * wv0.y + h4.y * wv1.y + h4.z * wv2.y + h4.w * wv3.y;
        az  += h4.x * wv0.z + h4.y * wv1.z + h4.z * wv2.z + h4.w * wv3.z;
        aww += h4.x * wv0.w + h4.y * wv1.w + h4.z * wv2.w + h4.w * wv3.w;
      }
      hv[pc][0] = tanhf(ax); hv[pc][1] = tanhf(ay);
      hv[pc][2] = tanhf(az); hv[pc][3] = tanhf(aww);
    }
    __syncthreads();  // all reads of hiddenL complete before overwrite
    pc = 0;
    for (int p = tid; p < 384; p += 256, pc++) {
      const int w = p >> 4, j0 = (p & 15) * 4;
      hiddenL[w * 68 + j0 + 0] = hv[pc][0]; hiddenL[w * 68 + j0 + 1] = hv[pc][1];
      hiddenL[w * 68 + j0 + 2] = hv[pc][2]; hiddenL[w * 68 + j0 + 3] = hv[pc][3];
    }
    __syncthreads();
  }

  // s[w] = h[w]·w2 + b2; output = mean over words
  if (tid < 24) {
    const int w = tid;
    float sv = out2_b[0];
    for (int j = 0; j < 64; j++) sv += hiddenL[w * 68 + j] * w2s[j];
    sred[w] = sv;
  }
  __syncthreads();
  if (tid == 0) {
    float s = 0.f;
    for (int w = 0; w < 24; w++) s += sred[w];
    out[n * 32 + c] = s * (1.0f / 24.0f);
  }
}

// ---------------------------------------------------------------------------
extern "C" void kernel_launch(void* const* d_in, const int* in_sizes, int n_in,
                              void* d_out, int out_size, void* d_ws, size_t ws_size,
                              hipStream_t stream) {
  const float* images   = (const float*)d_in[0];
  const float* captions = (const float*)d_in[1];
  const int*   depends  = (const int*)d_in[2];
  // d_in[3] cap_lens: unused by reference math (all == N_WORD)
  const float* mean_k   = (const float*)d_in[4];
  const float* prec_k   = (const float*)d_in[5];
  const float* conv_w   = (const float*)d_in[6];
  const float* out1_v   = (const float*)d_in[7];
  const float* out1_g   = (const float*)d_in[8];
  const float* out1_b   = (const float*)d_in[9];
  const float* out2_v   = (const float*)d_in[10];
  const float* out2_g   = (const float*)d_in[11];
  const float* out2_b   = (const float*)d_in[12];
  float* ws  = (float*)d_ws;
  float* out = (float*)d_out;

  prep_weights_k<<<dim3(1), dim3(64), 0, stream>>>(out1_v, out1_g, out2_v, out2_g, ws);
  cap_prep_k<<<dim3(32), dim3(256), 0, stream>>>(captions, depends, mean_k, prec_k, ws);
  main_k<<<dim3(N_IMAGE * N_CAPTION), dim3(256), 0, stream>>>(
      images, captions, conv_w, out1_b, out2_b, ws, out);
}

// Round 11
// 509.838 us; speedup vs baseline: 2.9519x; 1.3884x over previous
//
#include <hip/hip_runtime.h>
#include <math.h>

// Problem constants
#define N_IMAGE   128
#define N_CAPTION 32
#define N_REGION  36
#define N_WORD    24
#define EMBED     1024
#define EPSV      1e-8f

// Workspace layout (float offsets)
#define WS_W1 0            // 64*64 weight-normed out1 W
#define WS_W2 4096         // 64 weight-normed out2 row
#define WS_S  4160         // 32 captions * 24 words * 8 kernels
#define WS_QN 10304        // 32 captions * 24 words * 32 blocks

// ---------------------------------------------------------------------------
// Kernel 1: weight-norm the two linear layers (tiny, 1 block)
// ---------------------------------------------------------------------------
__global__ __launch_bounds__(64) void prep_weights_k(
    const float* __restrict__ v1, const float* __restrict__ g1,
    const float* __restrict__ v2, const float* __restrict__ g2,
    float* __restrict__ ws) {
  const int j = threadIdx.x;  // 64 threads
  float s = 0.f;
  for (int c0 = 0; c0 < 64; c0++) { float x = v1[j * 64 + c0]; s += x * x; }
  const float sc = g1[j] / sqrtf(s);
  for (int c0 = 0; c0 < 64; c0++) ws[WS_W1 + j * 64 + c0] = v1[j * 64 + c0] * sc;
  float s2 = 0.f;
  for (int c0 = 0; c0 < 64; c0++) { float x = v2[c0]; s2 += x * x; }
  ws[WS_W2 + j] = v2[j] * (g2[0] / sqrtf(s2));
}

// ---------------------------------------------------------------------------
// Kernel 2: per-caption precompute: words_sim softmax, adjacency, S[i][k],
// cap block-norms qn[w][f].  One block per caption.  (unchanged)
// ---------------------------------------------------------------------------
__global__ __launch_bounds__(256) void cap_prep_k(
    const float* __restrict__ captions, const int* __restrict__ depends,
    const float* __restrict__ mean_k, const float* __restrict__ prec_k,
    float* __restrict__ ws) {
  __shared__ __align__(16) float capT[24][132];
  __shared__ float partB[2304];   // 4 groups * 576
  __shared__ float wsL[24][25];
  __shared__ float adjL[24][24];

  const int c = blockIdx.x, tid = threadIdx.x;
  const float* capC = captions + c * N_WORD * EMBED;

  const int g = tid / 36, t = tid % 36;
  const int i0 = (t / 6) * 4, j0 = (t % 6) * 4;
  const bool act = tid < 144;
  float acc[4][4] = {};
  for (int k0 = 0; k0 < EMBED; k0 += 128) {
    for (int idx = tid; idx < 24 * 32; idx += 256) {
      int r = idx >> 5, q = idx & 31;
      *(float4*)&capT[r][q * 4] = *(const float4*)(capC + r * EMBED + k0 + q * 4);
    }
    __syncthreads();
    if (act) {
#pragma unroll
      for (int q8 = 0; q8 < 8; q8++) {
        const int q = g * 8 + q8;
        float4 av[4], bv[4];
#pragma unroll
        for (int a = 0; a < 4; a++) av[a] = *(const float4*)&capT[i0 + a][q * 4];
#pragma unroll
        for (int b = 0; b < 4; b++) bv[b] = *(const float4*)&capT[j0 + b][q * 4];
#pragma unroll
        for (int a = 0; a < 4; a++)
#pragma unroll
          for (int b = 0; b < 4; b++)
            acc[a][b] += av[a].x * bv[b].x + av[a].y * bv[b].y +
                         av[a].z * bv[b].z + av[a].w * bv[b].w;
      }
    }
    __syncthreads();
  }
  if (act)
#pragma unroll
    for (int a = 0; a < 4; a++)
#pragma unroll
      for (int b = 0; b < 4; b++)
        partB[g * 576 + (i0 + a) * 24 + (j0 + b)] = acc[a][b];
  __syncthreads();
  for (int p = tid; p < 576; p += 256)
    wsL[p / 24][p % 24] = partB[p] + partB[p + 576] + partB[p + 1152] + partB[p + 1728];
  {
    float* ap = &adjL[0][0];
    for (int p = tid; p < 576; p += 256) ap[p] = 0.f;
  }
  __syncthreads();
  if (tid < 24) {
    const int i = tid;
    float m = -1e30f;
    for (int j = 0; j < 24; j++) m = fmaxf(m, wsL[i][j]);
    float ssum = 0.f;
    for (int j = 0; j < 24; j++) {
      float e = expf(4.0f * (wsL[i][j] - m));
      wsL[i][j] = e; ssum += e;
    }
    float inv = 1.0f / ssum;
    for (int j = 0; j < 24; j++) wsL[i][j] *= inv;
  }
  __syncthreads();
  if (tid >= 1 && tid < 23) {
    int r = depends[c * 46 + tid * 2];
    int cc = depends[c * 46 + tid * 2 + 1];
    if ((unsigned)r < 24u && (unsigned)cc < 24u) {
      adjL[r][cc] = 1.f;
      adjL[cc][r] = 1.f;
    }
  }
  __syncthreads();
  if (tid < 24) adjL[tid][tid] += 1.f;
  __syncthreads();
  if (tid < 24) {
    const int i = tid;
    float mk[8], pk2[8];
#pragma unroll
    for (int k = 0; k < 8; k++) {
      mk[k] = mean_k[k];
      float p = prec_k[k];
      pk2[k] = 1e-14f + p * p;
    }
    float s2 = 0.f;
    for (int j = 0; j < 24; j++) {
      float a = adjL[i][j] * wsL[i][j];
      s2 += a * a;
    }
    const float inv = 1.0f / (sqrtf(s2) + EPSV);
    float accS[8] = {};
    for (int j = 0; j < 24; j++) {
      const float adj_ij = adjL[i][j];
      if (adj_ij != 0.f) {
        const float nb = adj_ij * wsL[i][j] * inv;
        float wk[8], ssum = 0.f;
#pragma unroll
        for (int k = 0; k < 8; k++) {
          float d = nb - mk[k];
          wk[k] = expf(-0.5f * d * d / pk2[k]);
          ssum += wk[k];
        }
        const float invs = adj_ij / ssum;
#pragma unroll
        for (int k = 0; k < 8; k++) accS[k] += wk[k] * invs;
      }
    }
#pragma unroll
    for (int k = 0; k < 8; k++) ws[WS_S + (c * 24 + i) * 8 + k] = accS[k];
  }
  for (int p = tid; p < 768; p += 256) {
    const int w = p >> 5, f = p & 31;
    const float* q = capC + w * EMBED + f * 32;
    float s = 0.f;
#pragma unroll
    for (int d = 0; d < 32; d += 4) {
      float4 v = *(const float4*)(q + d);
      s += v.x * v.x + v.y * v.y + v.z * v.z + v.w * v.w;
    }
    ws[WS_QN + (c * 24 + w) * 32 + f] = sqrtf(s);
  }
}

// ---------------------------------------------------------------------------
// Kernel 3: main — one block per (image n, caption-PAIR c0,c0+1). R11 CTILE=2:
//   R10 analysis: 640us at VALU 41%, HBM 3% -> barrier/latency-bound; img
//   staged twice per pair (8192x total), ~41 barriers/pair of thin compute.
//   Sharing one image across 2 captions: img staging & iv reads & W1t staging
//   halve per pair; barriers/pair ~41 -> ~23; compute per barrier interval 2x.
//   Stage 1 keeps acc[4][4]=16 regs via 2-way split-K over 36x48 (216 thr).
//   Stage 3 carries 6 float4 acc (c0+c1) per thread. LDS 52416B -> 3 blk/CU
//   (6 resident pairs vs 4). Grid 2048.
// ---------------------------------------------------------------------------
__global__ __launch_bounds__(256, 2) void main_k(
    const float* __restrict__ images, const float* __restrict__ captions,
    const float* __restrict__ conv_w, const float* __restrict__ out1_b,
    const float* __restrict__ out2_b, const float* __restrict__ ws,
    float* __restrict__ out) {
  // bufA: img chunk (swizzled 36x132) / split-K partials (3456) / W1t (64x68)
  // bufB: capT 2 captions (48x132)    / tnode[2][24][33] + hiddenL (24x68)
  // bufC: attn [2][36][28]            / {Ss[384], w2s[64], b1s[64], sred[24]}
  __shared__ __align__(16) float bufA[36 * 132];      // 19008 B
  __shared__ __align__(16) float bufB[48 * 132];      // 25344 B
  __shared__ __align__(16) float bufC[2 * 36 * 28];   //  8064 B => 52416 B

  const int tid = threadIdx.x;
  const int bid = blockIdx.x;
  const int n = bid >> 4, c0 = (bid & 15) * 2;
  const float* imgN = images + n * N_REGION * EMBED;
  const float* capB = captions + c0 * N_WORD * EMBED;  // 48 contiguous rows

  // ============ stage 1: attn_raw = leaky_relu(img @ [cap0;cap1]^T) ============
  // 216 active threads, 2-way split-K, 4x4 register tiles over 36x48 outputs.
  const int g1 = tid / 108, t1 = tid % 108;
  const int r0 = (t1 / 12) * 4, w0 = (t1 % 12) * 4;   // w0 in 0..44 (2 captions)
  const bool act1 = tid < 216;
  const int si = (r0 >> 2) & 7, sc = (w0 >> 2) & 7;   // bank swizzles
  float acc1[4][4] = {};

  for (int k0 = 0; k0 < EMBED; k0 += 128) {
    for (int idx = tid; idx < 36 * 32; idx += 256) {
      const int r = idx >> 5, q = idx & 31;
      *(float4*)&bufA[r * 132 + (q ^ ((r >> 2) & 7)) * 4] =
          *(const float4*)(imgN + r * EMBED + k0 + q * 4);
    }
    for (int idx = tid; idx < 48 * 32; idx += 256) {
      const int r = idx >> 5, q = idx & 31;
      *(float4*)&bufB[r * 132 + (q ^ ((r >> 2) & 7)) * 4] =
          *(const float4*)(capB + r * EMBED + k0 + q * 4);
    }
    __syncthreads();
    if (act1) {
#pragma unroll 8
      for (int qq = 0; qq < 16; qq++) {
        const int q = g1 * 16 + qq;
        float4 av[4];
#pragma unroll
        for (int a = 0; a < 4; a++)
          av[a] = *(const float4*)&bufA[(r0 + a) * 132 + (q ^ si) * 4];
#pragma unroll
        for (int b = 0; b < 4; b++) {
          const float4 bv = *(const float4*)&bufB[(w0 + b) * 132 + (q ^ sc) * 4];
#pragma unroll
          for (int a = 0; a < 4; a++)
            acc1[a][b] += av[a].x * bv.x + av[a].y * bv.y +
                          av[a].z * bv.z + av[a].w * bv.w;
        }
      }
    }
    __syncthreads();
  }
  {
    float* part = bufA;  // 2 groups * 1728 = 3456 floats (img dead)
    if (act1) {
#pragma unroll
      for (int a = 0; a < 4; a++)
#pragma unroll
        for (int b = 0; b < 4; b++)
          part[g1 * 1728 + (r0 + a) * 48 + (w0 + b)] = acc1[a][b];
    }
    __syncthreads();
    for (int p = tid; p < 1728; p += 256) {
      float s = part[p] + part[p + 1728];
      const int r = p / 48, w = p % 48;
      const int cc = w / 24, wl = w % 24;
      bufC[cc * 1008 + r * 28 + wl] = (s > 0.f) ? s : 0.1f * s;  // leaky 0.1
    }
    __syncthreads();
  }

  // ============ stage 2: l2norm over words (per region), softmax over regions ============
  if (tid < 72) {
    const int cc = tid / 36, r = tid % 36;
    float* row = bufC + cc * 1008 + r * 28;
    float s = 0.f;
    for (int w = 0; w < 24; w++) { float x = row[w]; s += x * x; }
    const float inv = 1.f / (sqrtf(s) + EPSV);
    for (int w = 0; w < 24; w++) row[w] *= inv;
  }
  __syncthreads();
  if (tid < 48) {
    const int cc = tid / 24, w = tid % 24;
    float* colb = bufC + cc * 1008 + w;
    float m = -1e30f;
    for (int r = 0; r < 36; r++) m = fmaxf(m, colb[r * 28]);
    float ssum = 0.f;
    for (int r = 0; r < 36; r++) {
      float e = expf(4.0f * (colb[r * 28] - m));
      colb[r * 28] = e; ssum += e;
    }
    const float inv = 1.0f / ssum;
    for (int r = 0; r < 36; r++) colb[r * 28] *= inv;
  }
  __syncthreads();

  // ============ stage 3: wctx (both captions) + block cosine -> tnode ============
  // 256 threads: wg3 = 3 words, dq = 16B unit. One iv load feeds BOTH captions'
  // accumulators (6x float4). cv loads deferred past the r-loop (R10 pattern).
  const int wg3 = (tid >> 5) * 3;
  const int dq = tid & 31;
  float* tn0 = bufB;          // tnode c0: [24][33] (capT dead)
  float* tn1 = bufB + 792;    // tnode c1
  for (int k0 = 0; k0 < EMBED; k0 += 128) {
    for (int idx = tid; idx < 36 * 32; idx += 256) {
      const int r = idx >> 5, q = idx & 31;
      *(float4*)&bufA[r * 132 + (q ^ ((r >> 2) & 7)) * 4] =
          *(const float4*)(imgN + r * EMBED + k0 + q * 4);
    }
    __syncthreads();
    {
      float4 a00 = make_float4(0.f, 0.f, 0.f, 0.f), a01 = a00, a02 = a00;
      float4 a10 = a00, a11 = a00, a12 = a00;
#pragma unroll 4
      for (int r = 0; r < 36; r++) {
        float4 iv = *(const float4*)&bufA[r * 132 + (dq ^ ((r >> 2) & 7)) * 4];
        const float* awr = bufC + r * 28 + wg3;
        const float b00 = awr[0],    b01 = awr[1],    b02 = awr[2];
        const float b10 = awr[1008], b11 = awr[1009], b12 = awr[1010];
        a00.x += b00 * iv.x; a00.y += b00 * iv.y; a00.z += b00 * iv.z; a00.w += b00 * iv.w;
        a01.x += b01 * iv.x; a01.y += b01 * iv.y; a01.z += b01 * iv.z; a01.w += b01 * iv.w;
        a02.x += b02 * iv.x; a02.y += b02 * iv.y; a02.z += b02 * iv.z; a02.w += b02 * iv.w;
        a10.x += b10 * iv.x; a10.y += b10 * iv.y; a10.z += b10 * iv.z; a10.w += b10 * iv.w;
        a11.x += b11 * iv.x; a11.y += b11 * iv.y; a11.z += b11 * iv.z; a11.w += b11 * iv.w;
        a12.x += b12 * iv.x; a12.y += b12 * iv.y; a12.z += b12 * iv.z; a12.w += b12 * iv.w;
      }
      // cap slices AFTER the r-loop: not live across it (pressure)
      const float* cp0 = capB + wg3 * EMBED + k0 + dq * 4;
      const float* cp1 = capB + (24 + wg3) * EMBED + k0 + dq * 4;
      float4 cv00 = *(const float4*)(cp0);
      float4 cv01 = *(const float4*)(cp0 + EMBED);
      float4 cv02 = *(const float4*)(cp0 + 2 * EMBED);
      float4 cv10 = *(const float4*)(cp1);
      float4 cv11 = *(const float4*)(cp1 + EMBED);
      float4 cv12 = *(const float4*)(cp1 + 2 * EMBED);
      float nu00 = a00.x*cv00.x + a00.y*cv00.y + a00.z*cv00.z + a00.w*cv00.w;
      float nu01 = a01.x*cv01.x + a01.y*cv01.y + a01.z*cv01.z + a01.w*cv01.w;
      float nu02 = a02.x*cv02.x + a02.y*cv02.y + a02.z*cv02.z + a02.w*cv02.w;
      float nu10 = a10.x*cv10.x + a10.y*cv10.y + a10.z*cv10.z + a10.w*cv10.w;
      float nu11 = a11.x*cv11.x + a11.y*cv11.y + a11.z*cv11.z + a11.w*cv11.w;
      float nu12 = a12.x*cv12.x + a12.y*cv12.y + a12.z*cv12.z + a12.w*cv12.w;
      float cz00 = a00.x*a00.x + a00.y*a00.y + a00.z*a00.z + a00.w*a00.w;
      float cz01 = a01.x*a01.x + a01.y*a01.y + a01.z*a01.z + a01.w*a01.w;
      float cz02 = a02.x*a02.x + a02.y*a02.y + a02.z*a02.z + a02.w*a02.w;
      float cz10 = a10.x*a10.x + a10.y*a10.y + a10.z*a10.z + a10.w*a10.w;
      float cz11 = a11.x*a11.x + a11.y*a11.y + a11.z*a11.z + a11.w*a11.w;
      float cz12 = a12.x*a12.x + a12.y*a12.y + a12.z*a12.z + a12.w*a12.w;
#pragma unroll
      for (int m = 1; m < 8; m <<= 1) {
        nu00 += __shfl_xor(nu00, m); cz00 += __shfl_xor(cz00, m);
        nu01 += __shfl_xor(nu01, m); cz01 += __shfl_xor(cz01, m);
        nu02 += __shfl_xor(nu02, m); cz02 += __shfl_xor(cz02, m);
        nu10 += __shfl_xor(nu10, m); cz10 += __shfl_xor(cz10, m);
        nu11 += __shfl_xor(nu11, m); cz11 += __shfl_xor(cz11, m);
        nu12 += __shfl_xor(nu12, m); cz12 += __shfl_xor(cz12, m);
      }
      if ((dq & 7) == 0) {
        const int f = (k0 >> 5) + (dq >> 3);
        const float* q0 = ws + WS_QN + (c0 * 24 + wg3) * 32 + f;
        const float* q1 = q0 + 24 * 32;
        tn0[(wg3 + 0) * 33 + f] = nu00 / fmaxf(q0[0]  * sqrtf(cz00), EPSV);
        tn0[(wg3 + 1) * 33 + f] = nu01 / fmaxf(q0[32] * sqrtf(cz01), EPSV);
        tn0[(wg3 + 2) * 33 + f] = nu02 / fmaxf(q0[64] * sqrtf(cz02), EPSV);
        tn1[(wg3 + 0) * 33 + f] = nu10 / fmaxf(q1[0]  * sqrtf(cz10), EPSV);
        tn1[(wg3 + 1) * 33 + f] = nu11 / fmaxf(q1[32] * sqrtf(cz11), EPSV);
        tn1[(wg3 + 2) * 33 + f] = nu12 / fmaxf(q1[64] * sqrtf(cz12), EPSV);
      }
    }
    __syncthreads();
  }

  // ============ stage 4: graph-conv collapse + weight-normed MLP (x2 captions) ============
  float* W1t = bufA;            // W1t[col*68 + j]; staged ONCE, used twice
  float* hiddenL = bufB + 1584; // pitch 68 (after tnode x2)
  float* Ss  = bufC;            // 384 floats: S for c0,c1 (contiguous in ws)
  float* w2s = bufC + 384;
  float* b1s = bufC + 448;
  float* sred = bufC + 512;
  for (int idx = tid; idx < 4096; idx += 256) {
    const int j = idx >> 6, col = idx & 63;
    W1t[col * 68 + j] = ws[WS_W1 + idx];
  }
  for (int p = tid; p < 384; p += 256) Ss[p] = ws[WS_S + c0 * 192 + p];
  if (tid < 64) w2s[tid] = ws[WS_W2 + tid];
  else if (tid < 128) b1s[tid - 64] = out1_b[tid - 64];
  __syncthreads();

  for (int cc = 0; cc < 2; cc++) {
    const float* tn = bufB + cc * 792;
    // hidden[w][k*8+o] = S[w,k] * sum_f tnode[w,f]*conv_w[k,f,o]
    for (int p = tid; p < 1536; p += 256) {
      const int w = p >> 6, col = p & 63, k = col >> 3, o = col & 7;
      const float* cw = conv_w + k * 256 + o;
      float tacc = 0.f;
#pragma unroll 8
      for (int f = 0; f < 32; f++) tacc += tn[w * 33 + f] * cw[f * 8];
      hiddenL[w * 68 + col] = Ss[cc * 192 + w * 8 + k] * tacc;
    }
    __syncthreads();

    // h = tanh(hidden @ W1^T + b1)
    float hv[2][4];
    {
      int pc = 0;
      for (int p = tid; p < 384; p += 256, pc++) {
        const int w = p >> 4, j0 = (p & 15) * 4;
        float ax = b1s[j0 + 0], ay = b1s[j0 + 1], az = b1s[j0 + 2], aww = b1s[j0 + 3];
#pragma unroll 4
        for (int col = 0; col < 64; col += 4) {
          float4 h4 = *(const float4*)&hiddenL[w * 68 + col];
          float4 wv0 = *(const float4*)&W1t[(col + 0) * 68 + j0];
          float4 wv1 = *(const float4*)&W1t[(col + 1) * 68 + j0];
          float4 wv2 = *(const float4*)&W1t[(col + 2) * 68 + j0];
          float4 wv3 = *(const float4*)&W1t[(col + 3) * 68 + j0];
          ax  += h4.x * wv0.x + h4.y * wv1.x + h4.z * wv2.x + h4.w * wv3.x;
          ay  += h4.x * wv0.y + h4.y * wv1.y + h4.z * wv2.y + h4.w * wv3.y;
          az  += h4.x * wv0.z + h4.y * wv1.z + h4.z * wv2.z + h4.w * wv3.z;
          aww += h4.x * wv0.w + h4.y * wv1.w + h4.z * wv2.w + h4.w * wv3.w;
        }
        hv[pc][0] = tanhf(ax); hv[pc][1] = tanhf(ay);
        hv[pc][2] = tanhf(az); hv[pc][3] = tanhf(aww);
      }
      __syncthreads();  // all reads of hiddenL complete before overwrite
      pc = 0;
      for (int p = tid; p < 384; p += 256, pc++) {
        const int w = p >> 4, j0 = (p & 15) * 4;
        hiddenL[w * 68 + j0 + 0] = hv[pc][0]; hiddenL[w * 68 + j0 + 1] = hv[pc][1];
        hiddenL[w * 68 + j0 + 2] = hv[pc][2]; hiddenL[w * 68 + j0 + 3] = hv[pc][3];
      }
      __syncthreads();
    }

    // s[w] = h[w]·w2 + b2; output = mean over words
    if (tid < 24) {
      const int w = tid;
      float sv = out2_b[0];
      for (int j = 0; j < 64; j++) sv += hiddenL[w * 68 + j] * w2s[j];
      sred[w] = sv;
    }
    __syncthreads();
    if (tid == 0) {
      float s = 0.f;
      for (int w = 0; w < 24; w++) s += sred[w];
      out[n * 32 + c0 + cc] = s * (1.0f / 24.0f);
    }
    __syncthreads();  // protect hiddenL/sred reuse by next caption
  }
}

// ---------------------------------------------------------------------------
extern "C" void kernel_launch(void* const* d_in, const int* in_sizes, int n_in,
                              void* d_out, int out_size, void* d_ws, size_t ws_size,
                              hipStream_t stream) {
  const float* images   = (const float*)d_in[0];
  const float* captions = (const float*)d_in[1];
  const int*   depends  = (const int*)d_in[2];
  // d_in[3] cap_lens: unused by reference math (all == N_WORD)
  const float* mean_k   = (const float*)d_in[4];
  const float* prec_k   = (const float*)d_in[5];
  const float* conv_w   = (const float*)d_in[6];
  const float* out1_v   = (const float*)d_in[7];
  const float* out1_g   = (const float*)d_in[8];
  const float* out1_b   = (const float*)d_in[9];
  const float* out2_v   = (const float*)d_in[10];
  const float* out2_g   = (const float*)d_in[11];
  const float* out2_b   = (const float*)d_in[12];
  float* ws  = (float*)d_ws;
  float* out = (float*)d_out;

  prep_weights_k<<<dim3(1), dim3(64), 0, stream>>>(out1_v, out1_g, out2_v, out2_g, ws);
  cap_prep_k<<<dim3(32), dim3(256), 0, stream>>>(captions, depends, mean_k, prec_k, ws);
  main_k<<<dim3(N_IMAGE * 16), dim3(256), 0, stream>>>(
      images, captions, conv_w, out1_b, out2_b, ws, out);
}